// Round 10
// baseline (25.992 us; speedup 1.0000x reference)
//
#include <hip/hip_runtime.h>

#define BS 1024
#define D_IN 512
#define D_OUT 512
#define N_MASKS 8

typedef short bf16x8 __attribute__((ext_vector_type(8)));
typedef float f32x4 __attribute__((ext_vector_type(4)));

// ws layout (bytes):
//   [0,    64)      int group offsets wsi[0..8]
//   [64,   4224)    int row-perm wsi[16 + p], p in [0,1024)
//   [8192, +4MB)    Wf: 8 masks x 16 kb x 32 cb x 1024B fragment blocks (r2 layout)
//   [XB_OFF, +1MB)  xb: 1024 x 512 bf16
#define WF_OFF_USH (8192 / 2)
#define WF_USH     (N_MASKS * 16 * 32 * 512)
#define XB_OFF_USH (WF_OFF_USH + WF_USH)

__device__ __forceinline__ ushort f2bf(float f) {
    union { float f; unsigned u; } x; x.f = f;
    unsigned r = (x.u + 0x7fffu + ((x.u >> 16) & 1u)) >> 16;  // RNE
    return (ushort)r;
}

// ---------------- Prepass v7 (byte-identical to round 7) ----------------
__global__ void __launch_bounds__(256) prep_kernel(
    const float* __restrict__ x, const int* __restrict__ state,
    const float* __restrict__ kern, const float* __restrict__ masks,
    int* __restrict__ wsi, ushort* __restrict__ wf, ushort* __restrict__ xb)
{
    __shared__ float prod[32][133];
    const int bx  = blockIdx.x;
    const int tid = threadIdx.x;

    if (bx < 512) {
        const int n  = bx >> 6;          // mask
        const int kb = (bx >> 2) & 15;   // 32-row k tile
        const int cg = bx & 3;           // 128-col tile
        const int k0 = kb * 32, c0 = cg * 128;
        const float* maskn = masks + (size_t)n * (D_IN * D_OUT);

        #pragma unroll
        for (int it = 0; it < 4; ++it) {
            const int i  = it * 256 + tid;      // [0,1024)
            const int r  = i >> 5;              // 0..31
            const int c4 = i & 31;              // 0..31 (x4 cols)
            const size_t gidx = (size_t)(k0 + r) * D_OUT + c0 + c4 * 4;
            const float4 kv = *(const float4*)&kern[gidx];
            const float4 mv = *(const float4*)&maskn[gidx];
            float* dst = &prod[r][c4 * 4];
            dst[0] = kv.x * mv.x; dst[1] = kv.y * mv.y;
            dst[2] = kv.z * mv.z; dst[3] = kv.w * mv.w;
        }
        __syncthreads();

        #pragma unroll
        for (int it = 0; it < 2; ++it) {
            const int c = it * 64 + (tid >> 2); // local col 0..127
            const int q = tid & 3;              // k subgroup g
            uint pk[4];
            #pragma unroll
            for (int h = 0; h < 4; ++h) {
                const float v0 = prod[q * 8 + 2 * h][c];
                const float v1 = prod[q * 8 + 2 * h + 1][c];
                pk[h] = (uint)f2bf(v0) | ((uint)f2bf(v1) << 16);
            }
            uint4 o; o.x = pk[0]; o.y = pk[1]; o.z = pk[2]; o.w = pk[3];
            const int cb = cg * 8 + (c >> 4);
            const int l  = q * 16 + (c & 15);
            *(uint4*)(wf + ((size_t)((n * 16 + kb) * 32 + cb)) * 512 + l * 8) = o;
        }
    } else if (bx < 768) {
        const int idx = (bx - 512) * 256 + tid;        // [0, 65536)
        const float4 a = ((const float4*)x)[idx * 2];
        const float4 b = ((const float4*)x)[idx * 2 + 1];
        uint4 o;
        o.x = (uint)f2bf(a.x) | ((uint)f2bf(a.y) << 16);
        o.y = (uint)f2bf(a.z) | ((uint)f2bf(a.w) << 16);
        o.z = (uint)f2bf(b.x) | ((uint)f2bf(b.y) << 16);
        o.w = (uint)f2bf(b.z) | ((uint)f2bf(b.w) << 16);
        *(uint4*)(xb + (size_t)idx * 8) = o;
    } else {
        __shared__ int cnt[N_MASKS];
        __shared__ int offs[N_MASKS + 1];
        if (tid < N_MASKS) cnt[tid] = 0;
        __syncthreads();
        int s[4];
        #pragma unroll
        for (int r = 0; r < 4; ++r) {
            s[r] = state[r * 256 + tid];
            atomicAdd(&cnt[s[r]], 1);
        }
        __syncthreads();
        if (tid == 0) {
            int acc = 0;
            for (int i = 0; i < N_MASKS; ++i) { offs[i] = acc; acc += cnt[i]; }
            offs[N_MASKS] = acc;
        }
        __syncthreads();
        if (tid <= N_MASKS) wsi[tid] = offs[tid];
        if (tid < N_MASKS) cnt[tid] = offs[tid];
        __syncthreads();
        #pragma unroll
        for (int r = 0; r < 4; ++r) {
            const int pos = atomicAdd(&cnt[s[r]], 1);
            wsi[16 + pos] = r * 256 + tid;
        }
    }
}

// ---------------- GEMM v6 (byte-identical to rounds 6/7) ----------------
__global__ void __launch_bounds__(256, 4) gemm_kernel(
    const ushort* __restrict__ xb, const ushort* __restrict__ wf,
    const int* __restrict__ wsi, float* __restrict__ out)
{
    const int n   = blockIdx.x;
    const int cb0 = blockIdx.y * 2;          // two 16-col fragments
    const int off0 = wsi[n];
    const int off1 = wsi[n + 1];
    const int gcnt = off1 - off0;

    const int tid  = threadIdx.x;
    const int lane = tid & 63;
    const int wid  = tid >> 6;               // K-quarter id
    const int g    = lane >> 4;
    const int cl   = lane & 15;

    __shared__ float red[3][2][64][4];       // partials from waves 1..3 (6 KB)

    const ushort* wp0 = wf + ((size_t)((n * 16 + wid * 4) * 32 + cb0)) * 512 + lane * 8;

    for (int rt = blockIdx.z; rt * 16 < gcnt; rt += 8) {
        const int p  = off0 + rt * 16 + cl;
        const int rv = (p < off1) ? wsi[16 + p] : -1;   // row at tile-position cl
        const ushort* xr = xb + (size_t)(rv < 0 ? 0 : rv) * D_IN + wid * 4 * 32 + g * 8;

        f32x4 acc0 = {0.f, 0.f, 0.f, 0.f};
        f32x4 acc1 = {0.f, 0.f, 0.f, 0.f};
        #pragma unroll
        for (int i = 0; i < 4; ++i) {        // kb = wid*4 + i
            const bf16x8 a  = *(const bf16x8*)(xr + i * 32);
            const bf16x8 b0 = *(const bf16x8*)(wp0 + (size_t)i * 32 * 512);
            const bf16x8 b1 = *(const bf16x8*)(wp0 + (size_t)i * 32 * 512 + 512);
            acc0 = __builtin_amdgcn_mfma_f32_16x16x32_bf16(a, b0, acc0, 0, 0, 0);
            acc1 = __builtin_amdgcn_mfma_f32_16x16x32_bf16(a, b1, acc1, 0, 0, 0);
        }

        if (wid) {
            *(f32x4*)&red[wid - 1][0][lane][0] = acc0;
            *(f32x4*)&red[wid - 1][1][lane][0] = acc1;
        }
        __syncthreads();
        if (wid == 0) {
            #pragma unroll
            for (int w = 0; w < 3; ++w) {
                acc0 += *(const f32x4*)&red[w][0][lane][0];
                acc1 += *(const f32x4*)&red[w][1][lane][0];
            }
            #pragma unroll
            for (int r = 0; r < 4; ++r) {
                const int brow = __shfl(rv, g * 4 + r);
                if (brow >= 0) {
                    float* op = out + (size_t)brow * D_OUT;
                    op[cb0 * 16 + cl]       = fmaxf(acc0[r], 0.f);
                    op[(cb0 + 1) * 16 + cl] = fmaxf(acc1[r], 0.f);
                }
            }
        }
        __syncthreads();   // protect red before next iteration
    }
}

extern "C" void kernel_launch(void* const* d_in, const int* in_sizes, int n_in,
                              void* d_out, int out_size, void* d_ws, size_t ws_size,
                              hipStream_t stream) {
    const float* x     = (const float*)d_in[0];
    const int*   state = (const int*)d_in[1];
    const float* kern  = (const float*)d_in[2];
    const float* masks = (const float*)d_in[3];
    float*  out = (float*)d_out;
    int*    wsi = (int*)d_ws;
    ushort* wsu = (ushort*)d_ws;

    prep_kernel<<<769, 256, 0, stream>>>(x, state, kern, masks,
                                         wsi, wsu + WF_OFF_USH, wsu + XB_OFF_USH);
    // MEASUREMENT ROUND: gemm launched 3x (idempotent -> identical out bytes).
    // dur = r7_dur + 2*G_warm  =>  G_warm = (dur - 15.45)/2.
    dim3 grid(N_MASKS, 16, 8);
    gemm_kernel<<<grid, 256, 0, stream>>>(wsu + XB_OFF_USH, wsu + WF_OFF_USH, wsi, out);
    gemm_kernel<<<grid, 256, 0, stream>>>(wsu + XB_OFF_USH, wsu + WF_OFF_USH, wsi, out);
    gemm_kernel<<<grid, 256, 0, stream>>>(wsu + XB_OFF_USH, wsu + WF_OFF_USH, wsi, out);
}

// Round 11
// 15.596 us; speedup vs baseline: 1.6666x; 1.6666x over previous
//
#include <hip/hip_runtime.h>

#define BS 1024
#define D_IN 512
#define D_OUT 512
#define N_MASKS 8

typedef short bf16x8 __attribute__((ext_vector_type(8)));
typedef float f32x4 __attribute__((ext_vector_type(4)));

// ws layout (bytes):
//   [0,    64)      int group offsets wsi[0..8]
//   [64,   4224)    int row-perm wsi[16 + p], p in [0,1024)
//   [8192, +4MB)    Wf: 8 masks x 16 kb x 32 cb x 1024B fragment blocks (r2 layout)
//   [XB_OFF, +1MB)  xb: 1024 x 512 bf16
#define WF_OFF_USH (8192 / 2)
#define WF_USH     (N_MASKS * 16 * 32 * 512)
#define XB_OFF_USH (WF_OFF_USH + WF_USH)

__device__ __forceinline__ ushort f2bf(float f) {
    union { float f; unsigned u; } x; x.f = f;
    unsigned r = (x.u + 0x7fffu + ((x.u >> 16) & 1u)) >> 16;  // RNE
    return (ushort)r;
}

// ---------------- Prepass v11: r7 phases, XCD-aligned Wf block decode ----------------
// Wf blocks [0,512): mask id = bx & 7 -> mask-n writer blocks land on XCD n
// (round-robin dispatch), same XCD as gemm's mask-n reader blocks (linear id % 8 = n).
// Dirty Wf lines are then local-L2 on the gemm's first touch.
// blocks [512,768): x->bf16.  768: counting sort.
__global__ void __launch_bounds__(256) prep_kernel(
    const float* __restrict__ x, const int* __restrict__ state,
    const float* __restrict__ kern, const float* __restrict__ masks,
    int* __restrict__ wsi, ushort* __restrict__ wf, ushort* __restrict__ xb)
{
    __shared__ float prod[32][133];
    const int bx  = blockIdx.x;
    const int tid = threadIdx.x;

    if (bx < 512) {
        const int n  = bx & 7;           // mask (fastest -> XCD n)
        const int w  = bx >> 3;          // [0,64)
        const int kb = w >> 2;           // 32-row k tile
        const int cg = w & 3;            // 128-col tile
        const int k0 = kb * 32, c0 = cg * 128;
        const float* maskn = masks + (size_t)n * (D_IN * D_OUT);

        #pragma unroll
        for (int it = 0; it < 4; ++it) {
            const int i  = it * 256 + tid;      // [0,1024)
            const int r  = i >> 5;              // 0..31
            const int c4 = i & 31;              // 0..31 (x4 cols)
            const size_t gidx = (size_t)(k0 + r) * D_OUT + c0 + c4 * 4;
            const float4 kv = *(const float4*)&kern[gidx];
            const float4 mv = *(const float4*)&maskn[gidx];
            float* dst = &prod[r][c4 * 4];
            dst[0] = kv.x * mv.x; dst[1] = kv.y * mv.y;
            dst[2] = kv.z * mv.z; dst[3] = kv.w * mv.w;
        }
        __syncthreads();

        #pragma unroll
        for (int it = 0; it < 2; ++it) {
            const int c = it * 64 + (tid >> 2); // local col 0..127
            const int q = tid & 3;              // k subgroup g
            uint pk[4];
            #pragma unroll
            for (int h = 0; h < 4; ++h) {
                const float v0 = prod[q * 8 + 2 * h][c];
                const float v1 = prod[q * 8 + 2 * h + 1][c];
                pk[h] = (uint)f2bf(v0) | ((uint)f2bf(v1) << 16);
            }
            uint4 o; o.x = pk[0]; o.y = pk[1]; o.z = pk[2]; o.w = pk[3];
            const int cb = cg * 8 + (c >> 4);
            const int l  = q * 16 + (c & 15);
            *(uint4*)(wf + ((size_t)((n * 16 + kb) * 32 + cb)) * 512 + l * 8) = o;
        }
    } else if (bx < 768) {
        const int idx = (bx - 512) * 256 + tid;        // [0, 65536)
        const float4 a = ((const float4*)x)[idx * 2];
        const float4 b = ((const float4*)x)[idx * 2 + 1];
        uint4 o;
        o.x = (uint)f2bf(a.x) | ((uint)f2bf(a.y) << 16);
        o.y = (uint)f2bf(a.z) | ((uint)f2bf(a.w) << 16);
        o.z = (uint)f2bf(b.x) | ((uint)f2bf(b.y) << 16);
        o.w = (uint)f2bf(b.z) | ((uint)f2bf(b.w) << 16);
        *(uint4*)(xb + (size_t)idx * 8) = o;
    } else {
        __shared__ int cnt[N_MASKS];
        __shared__ int offs[N_MASKS + 1];
        if (tid < N_MASKS) cnt[tid] = 0;
        __syncthreads();
        int s[4];
        #pragma unroll
        for (int r = 0; r < 4; ++r) {
            s[r] = state[r * 256 + tid];
            atomicAdd(&cnt[s[r]], 1);
        }
        __syncthreads();
        if (tid == 0) {
            int acc = 0;
            for (int i = 0; i < N_MASKS; ++i) { offs[i] = acc; acc += cnt[i]; }
            offs[N_MASKS] = acc;
        }
        __syncthreads();
        if (tid <= N_MASKS) wsi[tid] = offs[tid];
        if (tid < N_MASKS) cnt[tid] = offs[tid];
        __syncthreads();
        #pragma unroll
        for (int r = 0; r < 4; ++r) {
            const int pos = atomicAdd(&cnt[s[r]], 1);
            wsi[16 + pos] = r * 256 + tid;
        }
    }
}

// ---------------- GEMM v6 (byte-identical to rounds 6/7) ----------------
__global__ void __launch_bounds__(256, 4) gemm_kernel(
    const ushort* __restrict__ xb, const ushort* __restrict__ wf,
    const int* __restrict__ wsi, float* __restrict__ out)
{
    const int n   = blockIdx.x;
    const int cb0 = blockIdx.y * 2;          // two 16-col fragments
    const int off0 = wsi[n];
    const int off1 = wsi[n + 1];
    const int gcnt = off1 - off0;

    const int tid  = threadIdx.x;
    const int lane = tid & 63;
    const int wid  = tid >> 6;               // K-quarter id
    const int g    = lane >> 4;
    const int cl   = lane & 15;

    __shared__ float red[3][2][64][4];       // partials from waves 1..3 (6 KB)

    const ushort* wp0 = wf + ((size_t)((n * 16 + wid * 4) * 32 + cb0)) * 512 + lane * 8;

    for (int rt = blockIdx.z; rt * 16 < gcnt; rt += 8) {
        const int p  = off0 + rt * 16 + cl;
        const int rv = (p < off1) ? wsi[16 + p] : -1;   // row at tile-position cl
        const ushort* xr = xb + (size_t)(rv < 0 ? 0 : rv) * D_IN + wid * 4 * 32 + g * 8;

        f32x4 acc0 = {0.f, 0.f, 0.f, 0.f};
        f32x4 acc1 = {0.f, 0.f, 0.f, 0.f};
        #pragma unroll
        for (int i = 0; i < 4; ++i) {        // kb = wid*4 + i
            const bf16x8 a  = *(const bf16x8*)(xr + i * 32);
            const bf16x8 b0 = *(const bf16x8*)(wp0 + (size_t)i * 32 * 512);
            const bf16x8 b1 = *(const bf16x8*)(wp0 + (size_t)i * 32 * 512 + 512);
            acc0 = __builtin_amdgcn_mfma_f32_16x16x32_bf16(a, b0, acc0, 0, 0, 0);
            acc1 = __builtin_amdgcn_mfma_f32_16x16x32_bf16(a, b1, acc1, 0, 0, 0);
        }

        if (wid) {
            *(f32x4*)&red[wid - 1][0][lane][0] = acc0;
            *(f32x4*)&red[wid - 1][1][lane][0] = acc1;
        }
        __syncthreads();
        if (wid == 0) {
            #pragma unroll
            for (int w = 0; w < 3; ++w) {
                acc0 += *(const f32x4*)&red[w][0][lane][0];
                acc1 += *(const f32x4*)&red[w][1][lane][0];
            }
            #pragma unroll
            for (int r = 0; r < 4; ++r) {
                const int brow = __shfl(rv, g * 4 + r);
                if (brow >= 0) {
                    float* op = out + (size_t)brow * D_OUT;
                    op[cb0 * 16 + cl]       = fmaxf(acc0[r], 0.f);
                    op[(cb0 + 1) * 16 + cl] = fmaxf(acc1[r], 0.f);
                }
            }
        }
        __syncthreads();   // protect red before next iteration
    }
}

extern "C" void kernel_launch(void* const* d_in, const int* in_sizes, int n_in,
                              void* d_out, int out_size, void* d_ws, size_t ws_size,
                              hipStream_t stream) {
    const float* x     = (const float*)d_in[0];
    const int*   state = (const int*)d_in[1];
    const float* kern  = (const float*)d_in[2];
    const float* masks = (const float*)d_in[3];
    float*  out = (float*)d_out;
    int*    wsi = (int*)d_ws;
    ushort* wsu = (ushort*)d_ws;

    prep_kernel<<<769, 256, 0, stream>>>(x, state, kern, masks,
                                         wsi, wsu + WF_OFF_USH, wsu + XB_OFF_USH);
    dim3 grid(N_MASKS, 16, 8);
    gemm_kernel<<<grid, 256, 0, stream>>>(wsu + XB_OFF_USH, wsu + WF_OFF_USH, wsi, out);
}